// Round 1
// baseline (244.710 us; speedup 1.0000x reference)
//
#include <hip/hip_runtime.h>

#define NB 16     // batch
#define NN 512    // nodes
#define NF 64     // F_in == F_out
#define NE 16     // emb dim
#define NKF 192   // K*F_in

// ---------------- Kernel 1: D^-1/2 per row --------------------------------
// dis[b*N+n] = rsqrt(max(sum_m relu(A[b,n,m]) + 1, 1e-6))
__global__ void k_dinv(const float* __restrict__ A, float* __restrict__ dis) {
    int row = blockIdx.x * 4 + (threadIdx.x >> 6);   // 4 rows (waves) per block
    int lane = threadIdx.x & 63;
    const float* a = A + (size_t)row * NN;
    float s = 0.f;
    #pragma unroll
    for (int j = 0; j < NN / 64; ++j) s += fmaxf(a[lane + 64 * j], 0.f);
    #pragma unroll
    for (int off = 32; off >= 1; off >>= 1) s += __shfl_down(s, off, 64);
    if (lane == 0) dis[row] = rsqrtf(fmaxf(s + 1.0f, 1e-6f));
}

// ---------------- Kernel 2/3: y = Ahat @ xin  (MODE1: y = 2*Ahat@xin - xsub)
// Ahat computed on the fly: dis[n]*dis[m]*(relu(A[n,m]) + (n==m))
template <int MODE>
__global__ __launch_bounds__(256) void k_spmm(
    const float* __restrict__ A, const float* __restrict__ dis,
    const float* __restrict__ xin, const float* __restrict__ xsub,
    float* __restrict__ y) {
    int b = blockIdx.y;
    int n0 = blockIdx.x * 64;
    __shared__ float a_t[64][65];   // padded: reads a_t[r][m] across ty would 4-way conflict at 64
    __shared__ float x_t[64][64];   // [m][f], b128-friendly
    int tid = threadIdx.x;
    int tx = tid & 15, ty = tid >> 4;

    const float* Ab = A + (size_t)b * NN * NN;
    const float* Xb = xin + (size_t)b * NN * NF;
    const float* db = dis + b * NN;

    float acc[4][4] = {};

    for (int m0 = 0; m0 < NN; m0 += 64) {
        __syncthreads();   // previous compute done before overwriting tiles
        #pragma unroll
        for (int i = 0; i < 16; ++i) {
            int idx = tid + i * 256;          // 0..4095
            int r = idx >> 6, c = idx & 63;
            float av = Ab[(size_t)(n0 + r) * NN + m0 + c];
            av = fmaxf(av, 0.f);
            if (n0 + r == m0 + c) av += 1.0f;
            a_t[r][c] = av * db[n0 + r] * db[m0 + c];
            x_t[r][c] = Xb[(size_t)(m0 + r) * NF + c];
        }
        __syncthreads();
        #pragma unroll
        for (int m = 0; m < 64; ++m) {
            float bx[4], ar[4];
            #pragma unroll
            for (int i = 0; i < 4; ++i) bx[i] = x_t[m][tx * 4 + i];
            #pragma unroll
            for (int i = 0; i < 4; ++i) ar[i] = a_t[ty * 4 + i][m];
            #pragma unroll
            for (int i = 0; i < 4; ++i)
                #pragma unroll
                for (int j = 0; j < 4; ++j)
                    acc[i][j] = fmaf(ar[i], bx[j], acc[i][j]);
        }
    }

    float* Yb = y + (size_t)b * NN * NF;
    #pragma unroll
    for (int i = 0; i < 4; ++i) {
        int row = n0 + ty * 4 + i;
        #pragma unroll
        for (int j = 0; j < 4; ++j) {
            int col = tx * 4 + j;
            float v = acc[i][j];
            if (MODE == 1) v = 2.0f * v - xsub[((size_t)b * NN + row) * NF + col];
            Yb[(size_t)(row - n0 + n0) * NF + col] = v;  // row*NF+col
        }
    }
}

// ---------------- Kernel 4: adaptive output -------------------------------
// out[n,o] = sum_e emb[n,e] * ( sum_kf xg[n,kf]*Wp[e,kf,o] + bias[e,o] )
__global__ __launch_bounds__(256) void k_out(
    const float* __restrict__ x, const float* __restrict__ y1,
    const float* __restrict__ y2, const float* __restrict__ emb,
    const float* __restrict__ Wp, const float* __restrict__ bp,
    float* __restrict__ out) {
    int node0 = blockIdx.x * 32;                 // 32 nodes per block (flat over B*N)
    __shared__ float xg[32][NKF];
    __shared__ float embl[32][NE];
    int tid = threadIdx.x;

    const float* srcs[3] = {x, y1, y2};
    #pragma unroll
    for (int k = 0; k < 3; ++k) {
        const float* s = srcs[k];
        #pragma unroll
        for (int i = 0; i < 8; ++i) {
            int idx = tid + i * 256;             // 0..2047 -> 32 nodes x 64 f
            int nl = idx >> 6, f = idx & 63;
            xg[nl][k * 64 + f] = s[(size_t)(node0 + nl) * NF + f];
        }
    }
    #pragma unroll
    for (int i = 0; i < 2; ++i) {
        int idx = tid + i * 256;                 // 0..511 -> 32 x 16
        embl[idx >> 4][idx & 15] = emb[(size_t)node0 * NE + idx];
    }
    __syncthreads();

    int o = tid & 63, q = tid >> 6;              // o = output channel, q = wave id
    float acco[8] = {0.f, 0.f, 0.f, 0.f, 0.f, 0.f, 0.f, 0.f};

    #pragma unroll
    for (int e0 = 0; e0 < 4; ++e0) {             // e = e0 + 4*c
        float bv[4];
        float acce[4][8];
        #pragma unroll
        for (int c = 0; c < 4; ++c) {
            bv[c] = bp[(e0 + 4 * c) * NF + o];
            #pragma unroll
            for (int j = 0; j < 8; ++j) acce[c][j] = 0.f;
        }
        for (int kf = 0; kf < NKF; ++kf) {
            float w[4];
            #pragma unroll
            for (int c = 0; c < 4; ++c)
                w[c] = Wp[((size_t)(e0 + 4 * c) * NKF + kf) * NF + o];
            #pragma unroll
            for (int j = 0; j < 8; ++j) {
                float xv = xg[q + 4 * j][kf];
                #pragma unroll
                for (int c = 0; c < 4; ++c)
                    acce[c][j] = fmaf(xv, w[c], acce[c][j]);
            }
        }
        #pragma unroll
        for (int j = 0; j < 8; ++j) {
            int nl = q + 4 * j;
            #pragma unroll
            for (int c = 0; c < 4; ++c)
                acco[j] = fmaf(embl[nl][e0 + 4 * c], acce[c][j] + bv[c], acco[j]);
        }
    }

    #pragma unroll
    for (int j = 0; j < 8; ++j)
        out[(size_t)(node0 + q + 4 * j) * NF + o] = acco[j];
}

extern "C" void kernel_launch(void* const* d_in, const int* in_sizes, int n_in,
                              void* d_out, int out_size, void* d_ws, size_t ws_size,
                              hipStream_t stream) {
    const float* x   = (const float*)d_in[0];   // [16,512,64]
    const float* emb = (const float*)d_in[1];   // [16,512,16]
    const float* A   = (const float*)d_in[2];   // [16,512,512]
    const float* Wp  = (const float*)d_in[3];   // [16,3,64,64]
    const float* bp  = (const float*)d_in[4];   // [16,64]
    float* out = (float*)d_out;                 // [16,512,64]

    float* ws  = (float*)d_ws;
    float* dis = ws;                            // 8192 floats
    float* y1  = ws + 8192;                     // 524288 floats
    float* y2  = y1 + 524288;                   // 524288 floats

    k_dinv<<<NB * NN / 4, 256, 0, stream>>>(A, dis);
    dim3 g2(NN / 64, NB);
    k_spmm<0><<<g2, 256, 0, stream>>>(A, dis, x, nullptr, y1);
    k_spmm<1><<<g2, 256, 0, stream>>>(A, dis, y1, x, y2);
    k_out<<<NB * NN / 32, 256, 0, stream>>>(x, y1, y2, emb, Wp, bp, out);
}

// Round 2
// 88.659 us; speedup vs baseline: 2.7601x; 2.7601x over previous
//
#include <hip/hip_runtime.h>
#include <hip/hip_bf16.h>

#define NB 16     // batch
#define NN 512    // nodes
#define NF 64     // F_in == F_out
#define NE 16     // emb dim
#define NKF 192   // K*F_in
#define NNODE (NB*NN)   // 8192

typedef __hip_bfloat16 bf16;
typedef __attribute__((ext_vector_type(8))) short short8;
typedef __attribute__((ext_vector_type(4))) float f32x4;

typedef const __attribute__((address_space(1))) char gchar;
typedef __attribute__((address_space(3))) char lchar;

__device__ inline void gload16(const void* g, void* l) {
    __builtin_amdgcn_global_load_lds((gchar*)g, (lchar*)l, 16, 0, 0);
}

// ---------------- Kernel 1: D^-1/2 per row --------------------------------
__global__ void k_dinv(const float* __restrict__ A, float* __restrict__ dis) {
    int row = blockIdx.x * 4 + (threadIdx.x >> 6);
    int lane = threadIdx.x & 63;
    const float* a = A + (size_t)row * NN;
    float s = 0.f;
    #pragma unroll
    for (int j = 0; j < NN / 64; ++j) s += fmaxf(a[lane + 64 * j], 0.f);
    #pragma unroll
    for (int off = 32; off >= 1; off >>= 1) s += __shfl_down(s, off, 64);
    if (lane == 0) dis[row] = rsqrtf(fmaxf(s + 1.0f, 1e-6f));
}

// ---------------- pack x into xg[:, 0:64] as bf16 --------------------------
__global__ void k_packx(const float* __restrict__ x, bf16* __restrict__ xg) {
    int idx = blockIdx.x * 256 + threadIdx.x;      // 0..524287
    int node = idx >> 6, f = idx & 63;
    xg[(size_t)node * NKF + f] = __float2bfloat16(x[idx]);
}

// ---------------- Wp -> Bt transposed bf16 [1024][192] ---------------------
__global__ void k_wcvt(const float* __restrict__ Wp, bf16* __restrict__ Bt) {
    int idx = blockIdx.x * 256 + threadIdx.x;      // 0..196607
    int col = idx / NKF, kf = idx % NKF;           // col = e*64+o
    int e = col >> 6, o = col & 63;
    Bt[idx] = __float2bfloat16(Wp[(size_t)e * (NKF * NF) + (size_t)kf * NF + o]);
}

// ---------------- Kernel 2/3: y = Ahat @ xin (MODE1: 2*Ahat@xin - xsub) ----
template <int MODE>
__global__ __launch_bounds__(256) void k_spmm(
    const float* __restrict__ A, const float* __restrict__ dis,
    const float* __restrict__ xin, const float* __restrict__ xsub,
    float* __restrict__ y, bf16* __restrict__ xg) {
    int b = blockIdx.y;
    int n0 = blockIdx.x * 64;
    __shared__ float a_t[64][65];
    __shared__ float x_t[64][64];
    int tid = threadIdx.x;
    int tx = tid & 15, ty = tid >> 4;

    const float* Ab = A + (size_t)b * NN * NN;
    const float* Xb = xin + (size_t)b * NN * NF;
    const float* db = dis + b * NN;

    float acc[4][4] = {};

    for (int m0 = 0; m0 < NN; m0 += 64) {
        __syncthreads();
        #pragma unroll
        for (int i = 0; i < 16; ++i) {
            int idx = tid + i * 256;
            int r = idx >> 6, c = idx & 63;
            float av = Ab[(size_t)(n0 + r) * NN + m0 + c];
            av = fmaxf(av, 0.f);
            if (n0 + r == m0 + c) av += 1.0f;
            a_t[r][c] = av * db[n0 + r] * db[m0 + c];
            x_t[r][c] = Xb[(size_t)(m0 + r) * NF + c];
        }
        __syncthreads();
        #pragma unroll
        for (int m = 0; m < 64; ++m) {
            float bx[4], ar[4];
            #pragma unroll
            for (int i = 0; i < 4; ++i) bx[i] = x_t[m][tx * 4 + i];
            #pragma unroll
            for (int i = 0; i < 4; ++i) ar[i] = a_t[ty * 4 + i][m];
            #pragma unroll
            for (int i = 0; i < 4; ++i)
                #pragma unroll
                for (int j = 0; j < 4; ++j)
                    acc[i][j] = fmaf(ar[i], bx[j], acc[i][j]);
        }
    }

    #pragma unroll
    for (int i = 0; i < 4; ++i) {
        int row = n0 + ty * 4 + i;
        size_t node = (size_t)b * NN + row;
        #pragma unroll
        for (int j = 0; j < 4; ++j) {
            int col = tx * 4 + j;
            float v = acc[i][j];
            if (MODE == 1) v = 2.0f * v - xsub[node * NF + col];
            if (MODE == 0) {
                y[node * NF + col] = v;
                xg[node * NKF + 64 + col] = __float2bfloat16(v);
            } else {
                xg[node * NKF + 128 + col] = __float2bfloat16(v);
            }
        }
    }
}

// ---------------- Kernel 4: t = Xg @ Bt^T  (bf16 MFMA, 128x128 tile) -------
// Xg: [8192][192] bf16, Bt: [1024][192] bf16 (row = output col, pre-transposed)
// t:  [8192][512] bf16  (one 512-col half per launch; colblk selects Bt rows)
__global__ __launch_bounds__(256) void k_gemm(
    const short* __restrict__ xg, const short* __restrict__ Bt,
    bf16* __restrict__ t, int colblk) {
    __shared__ short As[128 * 32];
    __shared__ short Bs[128 * 32];
    int tid = threadIdx.x;
    int lane = tid & 63;
    int w = tid >> 6;
    int n0 = blockIdx.x * 128;                 // node base
    int c0 = colblk * 512 + blockIdx.y * 128;  // Bt row base

    // staging: thread covers 16B chunks at LDS bytes tid*16 and tid*16+4096
    int rA0 = tid >> 2;            // row of chunk0 (64B rows)
    int p   = tid & 3;             // stored chunk slot
    int cA  = p ^ ((rA0 >> 1) & 3);   // logical chunk (XOR swizzle); same for rA0+64

    // fragment LDS element offsets (swizzled): row*32 + ((c ^ ((row>>1)&3))*8)
    int fr = lane & 15;            // row-within-16
    int fc = ((lane >> 4) ^ ((fr >> 1) & 3)) * 8;

    f32x4 acc[4][4] = {};

    for (int kt = 0; kt < 6; ++kt) {
        __syncthreads();
        gload16(xg + (size_t)(n0 + rA0) * NKF + kt * 32 + cA * 8, As + tid * 8);
        gload16(xg + (size_t)(n0 + rA0 + 64) * NKF + kt * 32 + cA * 8, As + 2048 + tid * 8);
        gload16(Bt + (size_t)(c0 + rA0) * NKF + kt * 32 + cA * 8, Bs + tid * 8);
        gload16(Bt + (size_t)(c0 + rA0 + 64) * NKF + kt * 32 + cA * 8, Bs + 2048 + tid * 8);
        __syncthreads();

        int wr = w >> 1, wc = w & 1;
        short8 a[4], b[4];
        #pragma unroll
        for (int i = 0; i < 4; ++i)
            a[i] = *(const short8*)&As[(wr * 64 + i * 16 + fr) * 32 + fc];
        #pragma unroll
        for (int j = 0; j < 4; ++j)
            b[j] = *(const short8*)&Bs[(wc * 64 + j * 16 + fr) * 32 + fc];
        #pragma unroll
        for (int i = 0; i < 4; ++i)
            #pragma unroll
            for (int j = 0; j < 4; ++j)
                acc[i][j] = __builtin_amdgcn_mfma_f32_16x16x32_bf16(a[i], b[j], acc[i][j], 0, 0, 0);
    }

    int wr = w >> 1, wc = w & 1;
    #pragma unroll
    for (int i = 0; i < 4; ++i) {
        #pragma unroll
        for (int j = 0; j < 4; ++j) {
            #pragma unroll
            for (int r = 0; r < 4; ++r) {
                int m = n0 + wr * 64 + i * 16 + (lane >> 4) * 4 + r;
                int cc = blockIdx.y * 128 + wc * 64 + j * 16 + (lane & 15);
                t[(size_t)m * 512 + cc] = __float2bfloat16(acc[i][j][r]);
            }
        }
    }
}

// ---------------- Kernel 5: out[n,o] (+)= sum_e emb*(t + bias) -------------
template <int H>
__global__ void k_reduce(const bf16* __restrict__ t, const float* __restrict__ emb,
                         const float* __restrict__ bp, float* __restrict__ out) {
    int gid = blockIdx.x * 256 + threadIdx.x;      // 0..524287
    int node = gid >> 6, o = gid & 63;
    float s = 0.f;
    #pragma unroll
    for (int e = 0; e < 8; ++e) {
        float tv = __bfloat162float(t[(size_t)node * 512 + e * 64 + o]);
        float bv = bp[(H * 8 + e) * NF + o];
        float ev = emb[(size_t)node * NE + H * 8 + e];
        s = fmaf(ev, tv + bv, s);
    }
    if (H) out[gid] += s; else out[gid] = s;
}

extern "C" void kernel_launch(void* const* d_in, const int* in_sizes, int n_in,
                              void* d_out, int out_size, void* d_ws, size_t ws_size,
                              hipStream_t stream) {
    const float* x   = (const float*)d_in[0];   // [16,512,64]
    const float* emb = (const float*)d_in[1];   // [16,512,16]
    const float* A   = (const float*)d_in[2];   // [16,512,512]
    const float* Wp  = (const float*)d_in[3];   // [16,3,64,64]
    const float* bp  = (const float*)d_in[4];   // [16,64]
    float* out = (float*)d_out;                 // [16,512,64]

    float* ws  = (float*)d_ws;
    float* dis = ws;                                  // 8192 f32
    float* y1  = ws + 8192;                           // 524288 f32
    bf16*  xg  = (bf16*)(ws + 8192 + 524288);         // 8192*192 bf16
    bf16*  Bt  = (bf16*)(ws + 1318912);               // 1024*192 bf16
    bf16*  t   = (bf16*)(ws + 1417216);               // 8192*512 bf16
    // total ws use: 3514368 f32-equiv = 14.06 MB

    k_dinv<<<NB * NN / 4, 256, 0, stream>>>(A, dis);
    k_packx<<<NNODE * NF / 256, 256, 0, stream>>>(x, xg);
    k_wcvt<<<(1024 * NKF) / 256, 256, 0, stream>>>(Wp, Bt);
    dim3 g2(NN / 64, NB);
    k_spmm<0><<<g2, 256, 0, stream>>>(A, dis, x, nullptr, y1, xg);
    k_spmm<1><<<g2, 256, 0, stream>>>(A, dis, y1, x, nullptr, xg);

    dim3 gg(NNODE / 128, 4);
    k_gemm<<<gg, 256, 0, stream>>>((const short*)xg, (const short*)Bt, t, 0);
    k_reduce<0><<<NNODE * NF / 256, 256, 0, stream>>>(t, emb, bp, out);
    k_gemm<<<gg, 256, 0, stream>>>((const short*)xg, (const short*)Bt, t, 1);
    k_reduce<1><<<NNODE * NF / 256, 256, 0, stream>>>(t, emb, bp, out);
}

// Round 5
// 76.146 us; speedup vs baseline: 3.2137x; 1.1643x over previous
//
#include <hip/hip_runtime.h>
#include <hip/hip_bf16.h>

#define NB 16     // batch
#define NN 512    // nodes
#define NF 64     // F_in == F_out
#define NE 16     // emb dim
#define NKF 192   // K*F_in
#define NNODE (NB*NN)   // 8192

typedef __hip_bfloat16 bf16;
typedef __attribute__((ext_vector_type(8))) short short8;
typedef __attribute__((ext_vector_type(4))) float f32x4;

typedef const __attribute__((address_space(1))) char gchar;
typedef __attribute__((address_space(3))) char lchar;

__device__ inline void gload16(const void* g, void* l) {
    __builtin_amdgcn_global_load_lds((gchar*)g, (lchar*)l, 16, 0, 0);
}

// ---------------- k_pre: fused dinv + packx + wcvt (R1-verified bodies) ----
// blocks [0,2048):    dis[row] = rsqrt(sum_m relu(A[row,m]) + 1)
// blocks [2048,4096): xg[:,0:64] = bf16(x)
// blocks [4096,4864): Bt[e*64+o][kf] = bf16(Wp[e][kf][o])
__global__ __launch_bounds__(256) void k_pre(
    const float* __restrict__ A, const float* __restrict__ x,
    const float* __restrict__ Wp, float* __restrict__ dis,
    bf16* __restrict__ xg, bf16* __restrict__ Bt) {
    int bid = blockIdx.x, tid = threadIdx.x;
    if (bid < 2048) {
        int row = bid * 4 + (tid >> 6);
        int lane = tid & 63;
        const float* a = A + (size_t)row * NN;
        float s = 0.f;
        #pragma unroll
        for (int j = 0; j < NN / 64; ++j) s += fmaxf(a[lane + 64 * j], 0.f);
        #pragma unroll
        for (int off = 32; off >= 1; off >>= 1) s += __shfl_down(s, off, 64);
        if (lane == 0) dis[row] = rsqrtf(fmaxf(s + 1.0f, 1e-6f));
    } else if (bid < 4096) {
        int idx = (bid - 2048) * 256 + tid;        // 0..524287
        int node = idx >> 6, f = idx & 63;
        xg[(size_t)node * NKF + f] = __float2bfloat16(x[idx]);
    } else {
        int idx = (bid - 4096) * 256 + tid;        // 0..196607
        int col = idx / NKF, kf = idx % NKF;       // col = e*64+o
        int e = col >> 6, o = col & 63;
        Bt[idx] = __float2bfloat16(Wp[(size_t)e * (NKF * NF) + (size_t)kf * NF + o]);
    }
}

// ---------------- k_spmm (R1-verified): y = Ahat @ xin --------------------
// MODE0: y1 = Ahat@x -> y (f32) + xg[:,64:128]; MODE1: y2 = 2*Ahat@y1 - x -> xg[:,128:192]
template <int MODE>
__global__ __launch_bounds__(256) void k_spmm(
    const float* __restrict__ A, const float* __restrict__ dis,
    const float* __restrict__ xin, const float* __restrict__ xsub,
    float* __restrict__ y, bf16* __restrict__ xg) {
    int b = blockIdx.y;
    int n0 = blockIdx.x * 64;
    __shared__ float a_t[64][65];
    __shared__ float x_t[64][64];
    int tid = threadIdx.x;
    int tx = tid & 15, ty = tid >> 4;

    const float* Ab = A + (size_t)b * NN * NN;
    const float* Xb = xin + (size_t)b * NN * NF;
    const float* db = dis + b * NN;

    float acc[4][4] = {};

    for (int m0 = 0; m0 < NN; m0 += 64) {
        __syncthreads();
        #pragma unroll
        for (int i = 0; i < 16; ++i) {
            int idx = tid + i * 256;
            int r = idx >> 6, c = idx & 63;
            float av = Ab[(size_t)(n0 + r) * NN + m0 + c];
            av = fmaxf(av, 0.f);
            if (n0 + r == m0 + c) av += 1.0f;
            a_t[r][c] = av * db[n0 + r] * db[m0 + c];
            x_t[r][c] = Xb[(size_t)(m0 + r) * NF + c];
        }
        __syncthreads();
        #pragma unroll
        for (int m = 0; m < 64; ++m) {
            float bx[4], ar[4];
            #pragma unroll
            for (int i = 0; i < 4; ++i) bx[i] = x_t[m][tx * 4 + i];
            #pragma unroll
            for (int i = 0; i < 4; ++i) ar[i] = a_t[ty * 4 + i][m];
            #pragma unroll
            for (int i = 0; i < 4; ++i)
                #pragma unroll
                for (int j = 0; j < 4; ++j)
                    acc[i][j] = fmaf(ar[i], bx[j], acc[i][j]);
        }
    }

    #pragma unroll
    for (int i = 0; i < 4; ++i) {
        int row = n0 + ty * 4 + i;
        size_t node = (size_t)b * NN + row;
        #pragma unroll
        for (int j = 0; j < 4; ++j) {
            int col = tx * 4 + j;
            float v = acc[i][j];
            if (MODE == 1) v = 2.0f * v - xsub[node * NF + col];
            if (MODE == 0) {
                y[node * NF + col] = v;
                xg[node * NKF + 64 + col] = __float2bfloat16(v);
            } else {
                xg[node * NKF + 128 + col] = __float2bfloat16(v);
            }
        }
    }
}

// ---------------- k_gemm: t = Xg @ Bt^T (bf16 MFMA, 128x128 tile) ----------
// Xg: [8192][192] bf16, Bt: [1024][192] bf16, t: [8192][1024] bf16
__global__ __launch_bounds__(256) void k_gemm(
    const short* __restrict__ xg, const short* __restrict__ Bt,
    bf16* __restrict__ t) {
    __shared__ short As[128 * 32];
    __shared__ short Bs[128 * 32];
    int tid = threadIdx.x;
    int lane = tid & 63;
    int w = tid >> 6;
    int n0 = blockIdx.x * 128;
    int c0 = blockIdx.y * 128;

    int rA0 = tid >> 2;
    int p   = tid & 3;
    int cA  = p ^ ((rA0 >> 1) & 3);

    int fr = lane & 15;
    int fc = ((lane >> 4) ^ ((fr >> 1) & 3)) * 8;

    f32x4 acc[4][4] = {};

    for (int kt = 0; kt < 6; ++kt) {
        __syncthreads();
        gload16(xg + (size_t)(n0 + rA0) * NKF + kt * 32 + cA * 8, As + tid * 8);
        gload16(xg + (size_t)(n0 + rA0 + 64) * NKF + kt * 32 + cA * 8, As + 2048 + tid * 8);
        gload16(Bt + (size_t)(c0 + rA0) * NKF + kt * 32 + cA * 8, Bs + tid * 8);
        gload16(Bt + (size_t)(c0 + rA0 + 64) * NKF + kt * 32 + cA * 8, Bs + 2048 + tid * 8);
        __syncthreads();

        int wr = w >> 1, wc = w & 1;
        short8 a[4], bfr[4];
        #pragma unroll
        for (int i = 0; i < 4; ++i)
            a[i] = *(const short8*)&As[(wr * 64 + i * 16 + fr) * 32 + fc];
        #pragma unroll
        for (int j = 0; j < 4; ++j)
            bfr[j] = *(const short8*)&Bs[(wc * 64 + j * 16 + fr) * 32 + fc];
        #pragma unroll
        for (int i = 0; i < 4; ++i)
            #pragma unroll
            for (int j = 0; j < 4; ++j)
                acc[i][j] = __builtin_amdgcn_mfma_f32_16x16x32_bf16(a[i], bfr[j], acc[i][j], 0, 0, 0);
    }

    int wr = w >> 1, wc = w & 1;
    #pragma unroll
    for (int i = 0; i < 4; ++i) {
        #pragma unroll
        for (int j = 0; j < 4; ++j) {
            #pragma unroll
            for (int r = 0; r < 4; ++r) {
                int m = n0 + wr * 64 + i * 16 + (lane >> 4) * 4 + r;
                int cc = c0 + wc * 64 + j * 16 + (lane & 15);
                t[(size_t)m * 1024 + cc] = __float2bfloat16(acc[i][j][r]);
            }
        }
    }
}

// ---------------- k_reduce: out = sum_e emb*(t + bias) ---------------------
__global__ void k_reduce(const bf16* __restrict__ t, const float* __restrict__ emb,
                         const float* __restrict__ bp, float* __restrict__ out) {
    int gid = blockIdx.x * 256 + threadIdx.x;      // 0..524287
    int node = gid >> 6, o = gid & 63;
    float s = 0.f;
    #pragma unroll
    for (int e = 0; e < NE; ++e) {
        float tv = __bfloat162float(t[(size_t)node * 1024 + e * 64 + o]);
        s = fmaf(emb[(size_t)node * NE + e], tv + bp[e * 64 + o], s);
    }
    out[gid] = s;
}

extern "C" void kernel_launch(void* const* d_in, const int* in_sizes, int n_in,
                              void* d_out, int out_size, void* d_ws, size_t ws_size,
                              hipStream_t stream) {
    const float* x   = (const float*)d_in[0];   // [16,512,64]
    const float* emb = (const float*)d_in[1];   // [16,512,16]
    const float* A   = (const float*)d_in[2];   // [16,512,512]
    const float* Wp  = (const float*)d_in[3];   // [16,3,64,64]
    const float* bp  = (const float*)d_in[4];   // [16,64]
    float* out = (float*)d_out;                 // [16,512,64]

    float* ws  = (float*)d_ws;
    float* dis = ws;                                  // 8192 f32
    float* y1  = ws + 8192;                           // 524288 f32
    bf16*  xg  = (bf16*)(ws + 8192 + 524288);         // 8192*192 bf16 = 786432 f32-eq
    bf16*  Bt  = (bf16*)(ws + 1318912);               // 1024*192 bf16 = 98304 f32-eq
    bf16*  t   = (bf16*)(ws + 1417216);               // 8192*1024 bf16 = 4194304 f32-eq
    // ws end: 5611520 f32 = 22.4 MB

    k_pre<<<4864, 256, 0, stream>>>(A, x, Wp, dis, xg, Bt);
    dim3 g2(NN / 64, NB);
    k_spmm<0><<<g2, 256, 0, stream>>>(A, dis, x, nullptr, y1, xg);
    k_spmm<1><<<g2, 256, 0, stream>>>(A, dis, y1, x, nullptr, xg);
    dim3 gg(NNODE / 128, 8);
    k_gemm<<<gg, 256, 0, stream>>>((const short*)xg, (const short*)Bt, t);
    k_reduce<<<NNODE * NF / 256, 256, 0, stream>>>(t, emb, bp, out);
}

// Round 6
// 70.106 us; speedup vs baseline: 3.4906x; 1.0862x over previous
//
#include <hip/hip_runtime.h>
#include <hip/hip_bf16.h>

#define NB 16     // batch
#define NN 512    // nodes
#define NF 64     // F_in == F_out
#define NE 16     // emb dim
#define NKF 192   // K*F_in
#define NNODE (NB*NN)   // 8192

typedef __hip_bfloat16 bf16;
typedef __attribute__((ext_vector_type(8))) short short8;
typedef __attribute__((ext_vector_type(4))) float f32x4;

typedef const __attribute__((address_space(1))) char gchar;
typedef __attribute__((address_space(3))) char lchar;

__device__ inline void gload16(const void* g, void* l) {
    __builtin_amdgcn_global_load_lds((gchar*)g, (lchar*)l, 16, 0, 0);
}

__device__ inline short f2bs(float f) {
    union { bf16 b; short s; } u; u.b = __float2bfloat16(f); return u.s;
}

// ---------------- k_pre: fused dinv + packx + wcvt -------------------------
// blocks [0,2048):     dis[row] = rsqrt(sum_m relu(A[row,m]) + 1)
// blocks [2048,2304):  xg[:,0:64] = bf16(x)   (8 elems/thread)
// blocks [2304,2352):  Bt[e*64+o][kf] = bf16(Wp[e][kf][o]) via LDS transpose
__global__ __launch_bounds__(256) void k_pre(
    const float* __restrict__ A, const float* __restrict__ x,
    const float* __restrict__ Wp, float* __restrict__ dis,
    bf16* __restrict__ xg, bf16* __restrict__ Bt) {
    __shared__ float Ts[64][66];
    int bid = blockIdx.x, tid = threadIdx.x;
    if (bid < 2048) {
        int row = bid * 4 + (tid >> 6);
        int lane = tid & 63;
        const float* a = A + (size_t)row * NN;
        float s = 0.f;
        #pragma unroll
        for (int j = 0; j < NN / 64; ++j) s += fmaxf(a[lane + 64 * j], 0.f);
        #pragma unroll
        for (int off = 32; off >= 1; off >>= 1) s += __shfl_down(s, off, 64);
        if (lane == 0) dis[row] = rsqrtf(fmaxf(s + 1.0f, 1e-6f));
    } else if (bid < 2304) {
        int gid = (bid - 2048) * 256 + tid;        // 0..65535, 8 f32 each
        int node = gid >> 3, f0 = (gid & 7) * 8;
        const float* xp = x + (size_t)node * NF + f0;
        short8 p;
        #pragma unroll
        for (int i = 0; i < 8; ++i) p[i] = f2bs(xp[i]);
        *(short8*)&xg[(size_t)node * NKF + f0] = p;
    } else {
        int q = bid - 2304;                        // 0..47
        int e = q >> 2, kq = q & 3;                // oops guard: 16e x 3kt -> use div
        e = q / 3; int kt = q % 3;
        // load 64 kf-rows x 64 o coalesced
        int r = tid >> 2, o0 = (tid & 3) * 16;
        const float* wp = Wp + (size_t)e * (NKF * NF) + (size_t)(kt * 64 + r) * NF + o0;
        #pragma unroll
        for (int i = 0; i < 4; ++i)
            *(float4*)&Ts[r][o0 + i * 4] = *(const float4*)(wp + i * 4);
        __syncthreads();
        // write transposed: Bt[(e*64+o)][kt*64 + r0..r0+15]
        int o = tid >> 2, r0 = (tid & 3) * 16;
        bf16* bt = Bt + (size_t)(e * 64 + o) * NKF + kt * 64 + r0;
        #pragma unroll
        for (int h = 0; h < 2; ++h) {
            short8 w;
            #pragma unroll
            for (int i = 0; i < 8; ++i) w[i] = f2bs(Ts[r0 + h * 8 + i][o]);
            *(short8*)&bt[h * 8] = w;
        }
        (void)kq;
    }
}

// ---------------- k_spmm: y = Ahat @ xin, 32x64 tile, grid 256 -------------
// MODE0: y1 = Ahat@x -> y (f32) + xg[:,64:128]; MODE1: y2 = 2*Ahat@y1 - x -> xg[:,128:192]
template <int MODE>
__global__ __launch_bounds__(256) void k_spmm(
    const float* __restrict__ A, const float* __restrict__ dis,
    const float* __restrict__ xin, const float* __restrict__ xsub,
    float* __restrict__ y, bf16* __restrict__ xg) {
    int b = blockIdx.y;
    int n0 = blockIdx.x * 32;
    __shared__ float a_tT[64][34];   // [m][n] scaled Ahat^T tile (+2 pad)
    __shared__ float x_t[64][64];    // [m][f]
    int tid = threadIdx.x;
    int tx = tid & 15, ty = tid >> 4;

    const float* Ab = A + (size_t)b * NN * NN;
    const float* Xb = xin + (size_t)b * NN * NF;
    const float* db = dis + b * NN;

    int ar_ = tid >> 3;              // A staging row 0..31
    int ac8 = (tid & 7) * 8;         // m-chunk base
    float dn = db[n0 + ar_];

    float acc[2][4] = {};

    for (int m0 = 0; m0 < NN; m0 += 64) {
        // issue global loads (overlap with prior compute)
        const float* ap = Ab + (size_t)(n0 + ar_) * NN + m0 + ac8;
        float4 a0 = *(const float4*)ap, a1 = *(const float4*)(ap + 4);
        float4 d0 = *(const float4*)(db + m0 + ac8);
        float4 d1 = *(const float4*)(db + m0 + ac8 + 4);
        float4 xv[4];
        #pragma unroll
        for (int i = 0; i < 4; ++i) {
            int f4 = tid + i * 256;          // 0..1023
            int r = f4 >> 4, c4 = f4 & 15;
            xv[i] = *(const float4*)&Xb[(size_t)(m0 + r) * NF + c4 * 4];
        }
        __syncthreads();   // prior iter's LDS reads done
        float av[8] = {a0.x, a0.y, a0.z, a0.w, a1.x, a1.y, a1.z, a1.w};
        float dm[8] = {d0.x, d0.y, d0.z, d0.w, d1.x, d1.y, d1.z, d1.w};
        #pragma unroll
        for (int i = 0; i < 8; ++i) {
            float v = fmaxf(av[i], 0.f) + ((n0 + ar_ == m0 + ac8 + i) ? 1.f : 0.f);
            a_tT[ac8 + i][ar_] = v * dn * dm[i];
        }
        #pragma unroll
        for (int i = 0; i < 4; ++i) {
            int f4 = tid + i * 256;
            int r = f4 >> 4, c4 = f4 & 15;
            *(float4*)&x_t[r][c4 * 4] = xv[i];
        }
        __syncthreads();
        #pragma unroll
        for (int m = 0; m < 64; ++m) {
            float2 ar2 = *(const float2*)&a_tT[m][ty * 2];
            float4 bx = *(const float4*)&x_t[m][tx * 4];
            acc[0][0] = fmaf(ar2.x, bx.x, acc[0][0]);
            acc[0][1] = fmaf(ar2.x, bx.y, acc[0][1]);
            acc[0][2] = fmaf(ar2.x, bx.z, acc[0][2]);
            acc[0][3] = fmaf(ar2.x, bx.w, acc[0][3]);
            acc[1][0] = fmaf(ar2.y, bx.x, acc[1][0]);
            acc[1][1] = fmaf(ar2.y, bx.y, acc[1][1]);
            acc[1][2] = fmaf(ar2.y, bx.z, acc[1][2]);
            acc[1][3] = fmaf(ar2.y, bx.w, acc[1][3]);
        }
    }

    #pragma unroll
    for (int i = 0; i < 2; ++i) {
        int row = n0 + ty * 2 + i;
        size_t node = (size_t)b * NN + row;
        #pragma unroll
        for (int j = 0; j < 4; ++j) {
            int col = tx * 4 + j;
            float v = acc[i][j];
            if (MODE == 1) v = 2.0f * v - xsub[node * NF + col];
            if (MODE == 0) {
                y[node * NF + col] = v;
                xg[node * NKF + 64 + col] = __float2bfloat16(v);
            } else {
                xg[node * NKF + 128 + col] = __float2bfloat16(v);
            }
        }
    }
}

// ---------------- k_gemm: t = Xg @ Bt^T (bf16 MFMA, 128x128 tile) ----------
// Xg: [8192][192] bf16, Bt: [1024][192] bf16, t: [8192][1024] bf16
__global__ __launch_bounds__(256) void k_gemm(
    const short* __restrict__ xg, const short* __restrict__ Bt,
    bf16* __restrict__ t) {
    __shared__ short As[128 * 32];
    __shared__ short Bs[128 * 32];
    int tid = threadIdx.x;
    int lane = tid & 63;
    int w = tid >> 6;
    int n0 = blockIdx.x * 128;
    int c0 = blockIdx.y * 128;

    int rA0 = tid >> 2;
    int p   = tid & 3;
    int cA  = p ^ ((rA0 >> 1) & 3);

    int fr = lane & 15;
    int fc = ((lane >> 4) ^ ((fr >> 1) & 3)) * 8;

    f32x4 acc[4][4] = {};

    for (int kt = 0; kt < 6; ++kt) {
        __syncthreads();
        gload16(xg + (size_t)(n0 + rA0) * NKF + kt * 32 + cA * 8, As + tid * 8);
        gload16(xg + (size_t)(n0 + rA0 + 64) * NKF + kt * 32 + cA * 8, As + 2048 + tid * 8);
        gload16(Bt + (size_t)(c0 + rA0) * NKF + kt * 32 + cA * 8, Bs + tid * 8);
        gload16(Bt + (size_t)(c0 + rA0 + 64) * NKF + kt * 32 + cA * 8, Bs + 2048 + tid * 8);
        __syncthreads();

        int wr = w >> 1, wc = w & 1;
        short8 a[4], bfr[4];
        #pragma unroll
        for (int i = 0; i < 4; ++i)
            a[i] = *(const short8*)&As[(wr * 64 + i * 16 + fr) * 32 + fc];
        #pragma unroll
        for (int j = 0; j < 4; ++j)
            bfr[j] = *(const short8*)&Bs[(wc * 64 + j * 16 + fr) * 32 + fc];
        #pragma unroll
        for (int i = 0; i < 4; ++i)
            #pragma unroll
            for (int j = 0; j < 4; ++j)
                acc[i][j] = __builtin_amdgcn_mfma_f32_16x16x32_bf16(a[i], bfr[j], acc[i][j], 0, 0, 0);
    }

    int wr = w >> 1, wc = w & 1;
    #pragma unroll
    for (int i = 0; i < 4; ++i) {
        #pragma unroll
        for (int j = 0; j < 4; ++j) {
            #pragma unroll
            for (int r = 0; r < 4; ++r) {
                int m = n0 + wr * 64 + i * 16 + (lane >> 4) * 4 + r;
                int cc = c0 + wc * 64 + j * 16 + (lane & 15);
                t[(size_t)m * 1024 + cc] = __float2bfloat16(acc[i][j][r]);
            }
        }
    }
}

// ---------------- k_reduce: out = sum_e emb*(t + bias) ---------------------
__global__ void k_reduce(const bf16* __restrict__ t, const float* __restrict__ emb,
                         const float* __restrict__ bp, float* __restrict__ out) {
    int gid = blockIdx.x * 256 + threadIdx.x;      // 0..524287
    int node = gid >> 6, o = gid & 63;
    float s = 0.f;
    #pragma unroll
    for (int e = 0; e < NE; ++e) {
        float tv = __bfloat162float(t[(size_t)node * 1024 + e * 64 + o]);
        s = fmaf(emb[(size_t)node * NE + e], tv + bp[e * 64 + o], s);
    }
    out[gid] = s;
}

extern "C" void kernel_launch(void* const* d_in, const int* in_sizes, int n_in,
                              void* d_out, int out_size, void* d_ws, size_t ws_size,
                              hipStream_t stream) {
    const float* x   = (const float*)d_in[0];   // [16,512,64]
    const float* emb = (const float*)d_in[1];   // [16,512,16]
    const float* A   = (const float*)d_in[2];   // [16,512,512]
    const float* Wp  = (const float*)d_in[3];   // [16,3,64,64]
    const float* bp  = (const float*)d_in[4];   // [16,64]
    float* out = (float*)d_out;                 // [16,512,64]

    float* ws  = (float*)d_ws;
    float* dis = ws;                                  // 8192 f32
    float* y1  = ws + 8192;                           // 524288 f32
    bf16*  xg  = (bf16*)(ws + 8192 + 524288);         // 8192*192 bf16 = 786432 f32-eq
    bf16*  Bt  = (bf16*)(ws + 1318912);               // 1024*192 bf16 = 98304 f32-eq
    bf16*  t   = (bf16*)(ws + 1417216);               // 8192*1024 bf16 = 4194304 f32-eq
    // ws end: 5611520 f32 = 22.4 MB

    k_pre<<<2352, 256, 0, stream>>>(A, x, Wp, dis, xg, Bt);
    dim3 g2(NN / 32, NB);
    k_spmm<0><<<g2, 256, 0, stream>>>(A, dis, x, nullptr, y1, xg);
    k_spmm<1><<<g2, 256, 0, stream>>>(A, dis, y1, x, nullptr, xg);
    dim3 gg(NNODE / 128, 8);
    k_gemm<<<gg, 256, 0, stream>>>((const short*)xg, (const short*)Bt, t);
    k_reduce<<<NNODE * NF / 256, 256, 0, stream>>>(t, emb, bp, out);
}

// Round 7
// 44.262 us; speedup vs baseline: 5.5286x; 1.5839x over previous
//
#include <hip/hip_runtime.h>
#include <hip/hip_bf16.h>

#define NB 16     // batch
#define NN 512    // nodes
#define NF 64     // F_in == F_out
#define NE 16     // emb dim
#define NKF 192   // K*F_in
#define NNODE (NB*NN)   // 8192

typedef __hip_bfloat16 bf16;
typedef __attribute__((ext_vector_type(8))) short short8;
typedef __attribute__((ext_vector_type(4))) float f32x4;

typedef const __attribute__((address_space(1))) char gchar;
typedef __attribute__((address_space(3))) char lchar;

__device__ inline void gload16(const void* g, void* l) {
    __builtin_amdgcn_global_load_lds((gchar*)g, (lchar*)l, 16, 0, 0);
}

__device__ inline short f2bs(float f) {
    union { bf16 b; short s; } u; u.b = __float2bfloat16(f); return u.s;
}

// ---------------- k_pre: fused dinv + x(pack+transpose) + wcvt -------------
// blocks [0,2048):     dis[row] = rsqrt(sum_m relu(A[row,m]) + 1)
// blocks [2048,2176):  xg[:,0:64] = bf16(x); xT[b][f][n] = bf16(x)^T
// blocks [2176,2224):  Bt[e*64+o][kf] = bf16(Wp[e][kf][o]) via LDS transpose
__global__ __launch_bounds__(256) void k_pre(
    const float* __restrict__ A, const float* __restrict__ x,
    const float* __restrict__ Wp, float* __restrict__ dis,
    bf16* __restrict__ xg, bf16* __restrict__ xT, bf16* __restrict__ Bt) {
    __shared__ float Ts[64][66];
    int bid = blockIdx.x, tid = threadIdx.x;
    if (bid < 2048) {
        int row = bid * 4 + (tid >> 6);
        int lane = tid & 63;
        const float* a = A + (size_t)row * NN;
        float s = 0.f;
        #pragma unroll
        for (int j = 0; j < NN / 64; ++j) s += fmaxf(a[lane + 64 * j], 0.f);
        #pragma unroll
        for (int off = 32; off >= 1; off >>= 1) s += __shfl_down(s, off, 64);
        if (lane == 0) dis[row] = rsqrtf(fmaxf(s + 1.0f, 1e-6f));
    } else if (bid < 2176) {
        int node0 = (bid - 2048) * 64;
        // load 64 nodes x 64 f coalesced; pack row-major to xg as we go
        int r = tid >> 2, f0 = (tid & 3) * 16;
        const float* xp = x + (size_t)(node0 + r) * NF + f0;
        float v[16];
        #pragma unroll
        for (int i = 0; i < 16; ++i) v[i] = xp[i];
        short8 p0, p1;
        #pragma unroll
        for (int i = 0; i < 8; ++i) { p0[i] = f2bs(v[i]); p1[i] = f2bs(v[8 + i]); }
        *(short8*)&xg[(size_t)(node0 + r) * NKF + f0] = p0;
        *(short8*)&xg[(size_t)(node0 + r) * NKF + f0 + 8] = p1;
        #pragma unroll
        for (int i = 0; i < 4; ++i)
            *(float4*)&Ts[r][f0 + i * 4] = *(const float4*)(v + i * 4);
        __syncthreads();
        // transposed write xT[b][f][n]
        int f = tid >> 2, nq0 = (tid & 3) * 16;
        int b = node0 >> 9, nloc = node0 & (NN - 1);
        bf16* xt = xT + (size_t)(b * NF + f) * NN + nloc + nq0;
        #pragma unroll
        for (int h = 0; h < 2; ++h) {
            short8 o;
            #pragma unroll
            for (int i = 0; i < 8; ++i) o[i] = f2bs(Ts[nq0 + h * 8 + i][f]);
            *(short8*)&xt[h * 8] = o;
        }
    } else {
        int q = bid - 2176;                        // 0..47
        int e = q / 3, kt = q % 3;
        int r = tid >> 2, o0 = (tid & 3) * 16;
        const float* wp = Wp + (size_t)e * (NKF * NF) + (size_t)(kt * 64 + r) * NF + o0;
        #pragma unroll
        for (int i = 0; i < 4; ++i)
            *(float4*)&Ts[r][o0 + i * 4] = *(const float4*)(wp + i * 4);
        __syncthreads();
        int o = tid >> 2, r0 = (tid & 3) * 16;
        bf16* bt = Bt + (size_t)(e * 64 + o) * NKF + kt * 64 + r0;
        #pragma unroll
        for (int h = 0; h < 2; ++h) {
            short8 w;
            #pragma unroll
            for (int i = 0; i < 8; ++i) w[i] = f2bs(Ts[r0 + h * 8 + i][o]);
            *(short8*)&bt[h * 8] = w;
        }
    }
}

// ---------------- k_ahat: Ah[b][n][m] = bf16(dn*dm*(relu(A)+I)) ------------
__global__ __launch_bounds__(256) void k_ahat(
    const float* __restrict__ A, const float* __restrict__ dis,
    bf16* __restrict__ Ah) {
    int tid = threadIdx.x;
    int row = blockIdx.x * 4 + (tid >> 6);         // global row 0..8191
    int m0 = (tid & 63) * 8;
    int b = row >> 9, n = row & (NN - 1);
    const float* db = dis + b * NN;
    float dn = db[n];
    const float* ap = A + (size_t)row * NN + m0;
    float4 a0 = *(const float4*)ap, a1 = *(const float4*)(ap + 4);
    float4 d0 = *(const float4*)(db + m0), d1 = *(const float4*)(db + m0 + 4);
    float av[8] = {a0.x, a0.y, a0.z, a0.w, a1.x, a1.y, a1.z, a1.w};
    float dm[8] = {d0.x, d0.y, d0.z, d0.w, d1.x, d1.y, d1.z, d1.w};
    short8 o;
    #pragma unroll
    for (int i = 0; i < 8; ++i) {
        float v = fmaxf(av[i], 0.f) + ((n == m0 + i) ? 1.f : 0.f);
        o[i] = f2bs(v * dn * dm[i]);
    }
    *(short8*)&Ah[(size_t)row * NN + m0] = o;
}

// ---------------- k_spmm (MFMA, k_gemm-pattern): C = Ah @ Bsrc^T -----------
// Ah rows: [n][m] bf16 (K=m); Bsrc rows: [f][m] bf16 (xT for PASS0, y1T for PASS1)
// PASS0: y1 = C -> xg[:,64:128] + y1T[b][f][n]
// PASS1: y2 = 2C - x -> xg[:,128:192]
template <int PASS>
__global__ __launch_bounds__(256) void k_spmm(
    const short* __restrict__ Ah, const short* __restrict__ Bsrc,
    const float* __restrict__ x, bf16* __restrict__ xg, bf16* __restrict__ y1T) {
    __shared__ short As[64 * 32];
    __shared__ short Xs[64 * 32];
    __shared__ float Cs[64][66];
    int tid = threadIdx.x, lane = tid & 63, w = tid >> 6;
    int n0 = blockIdx.x * 64, b = blockIdx.y;
    const short* Ab = Ah + (size_t)b * NN * NN;
    const short* Xb = Bsrc + (size_t)b * NF * NN;

    int sr = tid >> 2;                  // staging row 0..63
    int p  = tid & 3;                   // stored chunk slot
    int cA = p ^ ((sr >> 1) & 3);       // logical chunk (XOR swizzle)

    int fr = lane & 15;
    int fc = ((lane >> 4) ^ ((fr >> 1) & 3)) * 8;

    f32x4 acc[4] = {};

    for (int kt = 0; kt < 16; ++kt) {
        __syncthreads();
        gload16(Ab + (size_t)(n0 + sr) * NN + kt * 32 + cA * 8, As + tid * 8);
        gload16(Xb + (size_t)sr * NN + kt * 32 + cA * 8, Xs + tid * 8);
        __syncthreads();
        short8 afr = *(const short8*)&As[(16 * w + fr) * 32 + fc];
        #pragma unroll
        for (int j = 0; j < 4; ++j) {
            short8 bfr = *(const short8*)&Xs[(16 * j + fr) * 32 + fc];
            acc[j] = __builtin_amdgcn_mfma_f32_16x16x32_bf16(afr, bfr, acc[j], 0, 0, 0);
        }
    }

    // C[16w + 4*(lane>>4) + r][16j + (lane&15)] = acc[j][r]  (k_gemm C-layout)
    #pragma unroll
    for (int j = 0; j < 4; ++j)
        #pragma unroll
        for (int r = 0; r < 4; ++r)
            Cs[16 * w + 4 * (lane >> 4) + r][16 * j + (lane & 15)] = acc[j][r];
    __syncthreads();

    int nl = tid >> 2, f0 = (tid & 3) * 16;
    size_t node = (size_t)b * NN + n0 + nl;
    float cv[16];
    #pragma unroll
    for (int i = 0; i < 16; ++i) cv[i] = Cs[nl][f0 + i];
    if (PASS == 0) {
        short8 p0, p1;
        #pragma unroll
        for (int i = 0; i < 8; ++i) { p0[i] = f2bs(cv[i]); p1[i] = f2bs(cv[8 + i]); }
        *(short8*)&xg[node * NKF + 64 + f0] = p0;
        *(short8*)&xg[node * NKF + 64 + f0 + 8] = p1;
        // transposed write y1T[b][f][n]
        int f = tid >> 2, nq0 = (tid & 3) * 16;
        bf16* yt = y1T + (size_t)(b * NF + f) * NN + n0 + nq0;
        #pragma unroll
        for (int h = 0; h < 2; ++h) {
            short8 o;
            #pragma unroll
            for (int i = 0; i < 8; ++i) o[i] = f2bs(Cs[nq0 + h * 8 + i][f]);
            *(short8*)&yt[h * 8] = o;
        }
    } else {
        const float* xp = x + node * NF + f0;
        short8 p0, p1;
        #pragma unroll
        for (int i = 0; i < 8; ++i) {
            p0[i] = f2bs(2.f * cv[i] - xp[i]);
            p1[i] = f2bs(2.f * cv[8 + i] - xp[8 + i]);
        }
        *(short8*)&xg[node * NKF + 128 + f0] = p0;
        *(short8*)&xg[node * NKF + 128 + f0 + 8] = p1;
    }
}

// ---------------- k_gemm: t = Xg @ Bt^T (bf16 MFMA, 128x128 tile) ----------
// Xg: [8192][192] bf16, Bt: [1024][192] bf16, t: [8192][1024] bf16
__global__ __launch_bounds__(256) void k_gemm(
    const short* __restrict__ xg, const short* __restrict__ Bt,
    bf16* __restrict__ t) {
    __shared__ short As[128 * 32];
    __shared__ short Bs[128 * 32];
    int tid = threadIdx.x;
    int lane = tid & 63;
    int w = tid >> 6;
    int n0 = blockIdx.x * 128;
    int c0 = blockIdx.y * 128;

    int rA0 = tid >> 2;
    int p   = tid & 3;
    int cA  = p ^ ((rA0 >> 1) & 3);

    int fr = lane & 15;
    int fc = ((lane >> 4) ^ ((fr >> 1) & 3)) * 8;

    f32x4 acc[4][4] = {};

    for (int kt = 0; kt < 6; ++kt) {
        __syncthreads();
        gload16(xg + (size_t)(n0 + rA0) * NKF + kt * 32 + cA * 8, As + tid * 8);
        gload16(xg + (size_t)(n0 + rA0 + 64) * NKF + kt * 32 + cA * 8, As + 2048 + tid * 8);
        gload16(Bt + (size_t)(c0 + rA0) * NKF + kt * 32 + cA * 8, Bs + tid * 8);
        gload16(Bt + (size_t)(c0 + rA0 + 64) * NKF + kt * 32 + cA * 8, Bs + 2048 + tid * 8);
        __syncthreads();

        int wr = w >> 1, wc = w & 1;
        short8 a[4], bfr[4];
        #pragma unroll
        for (int i = 0; i < 4; ++i)
            a[i] = *(const short8*)&As[(wr * 64 + i * 16 + fr) * 32 + fc];
        #pragma unroll
        for (int j = 0; j < 4; ++j)
            bfr[j] = *(const short8*)&Bs[(wc * 64 + j * 16 + fr) * 32 + fc];
        #pragma unroll
        for (int i = 0; i < 4; ++i)
            #pragma unroll
            for (int j = 0; j < 4; ++j)
                acc[i][j] = __builtin_amdgcn_mfma_f32_16x16x32_bf16(a[i], bfr[j], acc[i][j], 0, 0, 0);
    }

    int wr = w >> 1, wc = w & 1;
    #pragma unroll
    for (int i = 0; i < 4; ++i) {
        #pragma unroll
        for (int j = 0; j < 4; ++j) {
            #pragma unroll
            for (int r = 0; r < 4; ++r) {
                int m = n0 + wr * 64 + i * 16 + (lane >> 4) * 4 + r;
                int cc = c0 + wc * 64 + j * 16 + (lane & 15);
                t[(size_t)m * 1024 + cc] = __float2bfloat16(acc[i][j][r]);
            }
        }
    }
}

// ---------------- k_reduce: out = sum_e emb*(t + bias) ---------------------
__global__ void k_reduce(const bf16* __restrict__ t, const float* __restrict__ emb,
                         const float* __restrict__ bp, float* __restrict__ out) {
    int gid = blockIdx.x * 256 + threadIdx.x;      // 0..524287
    int node = gid >> 6, o = gid & 63;
    float s = 0.f;
    #pragma unroll
    for (int e = 0; e < NE; ++e) {
        float tv = __bfloat162float(t[(size_t)node * 1024 + e * 64 + o]);
        s = fmaf(emb[(size_t)node * NE + e], tv + bp[e * 64 + o], s);
    }
    out[gid] = s;
}

extern "C" void kernel_launch(void* const* d_in, const int* in_sizes, int n_in,
                              void* d_out, int out_size, void* d_ws, size_t ws_size,
                              hipStream_t stream) {
    const float* x   = (const float*)d_in[0];   // [16,512,64]
    const float* emb = (const float*)d_in[1];   // [16,512,16]
    const float* A   = (const float*)d_in[2];   // [16,512,512]
    const float* Wp  = (const float*)d_in[3];   // [16,3,64,64]
    const float* bp  = (const float*)d_in[4];   // [16,64]
    float* out = (float*)d_out;                 // [16,512,64]

    float* ws  = (float*)d_ws;
    float* dis = ws;                                  // 8192 f32
    bf16*  xT  = (bf16*)(ws + 8192);                  // 16*64*512 bf16 = 262144 f32-eq
    bf16*  y1T = (bf16*)(ws + 270336);                // same
    bf16*  xg  = (bf16*)(ws + 532480);                // 8192*192 bf16 = 786432 f32-eq
    bf16*  Bt  = (bf16*)(ws + 1318912);               // 1024*192 bf16 = 98304 f32-eq
    bf16*  t   = (bf16*)(ws + 1417216);               // 8192*1024 bf16 = 4194304 f32-eq
    bf16*  Ah  = (bf16*)(ws + 5611520);               // 16*512*512 bf16 = 2097152 f32-eq
    // ws end: 7708672 f32 = 30.8 MB

    k_pre<<<2224, 256, 0, stream>>>(A, x, Wp, dis, xg, xT, Bt);
    k_ahat<<<2048, 256, 0, stream>>>(A, dis, Ah);
    dim3 g2(NN / 64, NB);
    k_spmm<0><<<g2, 256, 0, stream>>>((const short*)Ah, (const short*)xT, x, xg, y1T);
    k_spmm<1><<<g2, 256, 0, stream>>>((const short*)Ah, (const short*)y1T, x, xg, y1T);
    dim3 gg(NNODE / 128, 8);
    k_gemm<<<gg, 256, 0, stream>>>((const short*)xg, (const short*)Bt, t);
    k_reduce<<<NNODE * NF / 256, 256, 0, stream>>>(t, emb, bp, out);
}